// Round 4
// baseline (536.601 us; speedup 1.0000x reference)
//
#include <hip/hip_runtime.h>

// Problem constants
#define N4 4096
#define FF 32
#define KK 6
#define OO 128
#define BB 4

typedef __attribute__((ext_vector_type(8))) short  short8;   // 8 bf16 MFMA A/B frag
typedef __attribute__((ext_vector_type(4))) float  f32x4;
typedef __attribute__((ext_vector_type(4))) int    i32x4;
typedef __attribute__((ext_vector_type(2))) unsigned int u32x2;

__device__ __forceinline__ float b2f(unsigned short h) {
    union { float f; unsigned u; } v; v.u = ((unsigned)h) << 16; return v.f;
}
__device__ __forceinline__ unsigned short f2b(float f) {
    union { float f; unsigned u; } v; v.f = f;
    unsigned r = (v.u + 0x7FFFu + ((v.u >> 16) & 1u)) >> 16;
    return (unsigned short)r;
}

// Tb frag layout: element (f, n) of T lives at
//   tb_idx(b, ks=n>>5, half=f>>4, lane=((n>>3)&3)*16 + (f&15)) + (n&7)
__device__ __forceinline__ long tb_idx(int b, int ks, int half, int lane) {
    return ((((long)b * 128 + ks) * 2 + half) * 64 + lane) * 8;
}

// ---------------------------------------------------------------------------
__global__ __launch_bounds__(256) void make_wc(const float* __restrict__ W,
                                               const float* __restrict__ theta,
                                               unsigned short* __restrict__ Wc) {
    int idx = blockIdx.x * 256 + threadIdx.x;
    int k = idx >> 12;
    Wc[idx] = f2b(theta[k] * W[idx]);
}

// ---------------------------------------------------------------------------
// x [B][N][F] f32 -> T0 in Tb frag layout.  grid B*64=256 blocks (b, nc).
__global__ __launch_bounds__(256) void x_to_t(const float* __restrict__ x,
                                              unsigned short* __restrict__ T0) {
    __shared__ __align__(16) unsigned short Ol[32][72];   // [f][n-local]
    int tid = threadIdx.x, bid = blockIdx.x;
    int b = bid >> 6; int nc = bid & 63; long n0 = (long)nc * 64;
    int nl = tid >> 2, fg = (tid & 3) * 8;
    const float* src = x + ((long)b * N4 + n0 + nl) * FF + fg;
    f32x4 v0 = *(const f32x4*)src;
    f32x4 v1 = *(const f32x4*)(src + 4);
#pragma unroll
    for (int e = 0; e < 4; ++e) {
        Ol[fg + e][nl]     = f2b(v0[e]);
        Ol[fg + 4 + e][nl] = f2b(v1[e]);
    }
    __syncthreads();
    int ks_l = tid >> 7, half = (tid >> 6) & 1, lane = tid & 63;
    int quad = lane >> 4, l16 = lane & 15;
    int f = half * 16 + l16, nloc = ks_l * 32 + quad * 8;
    *(i32x4*)(T0 + tb_idx(b, nc * 2 + ks_l, half, lane)) = *(const i32x4*)&Ol[f][nloc];
}

// ---------------------------------------------------------------------------
// Pass 1 fused: reads f32 L (coalesced 256B/row chunks), wave-local LDS permute
// to frag layout, writes Lb (wave-contiguous 1KB) AND computes T1 = L @ T0.
// 4-slot register rotation, loads issued 3 iterations (~1KB x 12) ahead.
// grid 1024 blocks (b, ms) x 4 waves (s = split-k quarter). No __syncthreads.
__global__ __launch_bounds__(256) void gemm_pass1(const float* __restrict__ L,
                                                  unsigned short* __restrict__ Lb,
                                                  const unsigned short* __restrict__ Tb0,
                                                  float* __restrict__ P) {
    __shared__ __align__(16) unsigned short Sw[4][2][2][64][8];  // [wave][buf][ks_loc][lane][e]
    int tid = threadIdx.x, bid = blockIdx.x;
    int b = bid >> 8, ms = bid & 255;
    int w = tid >> 6, lane = tid & 63, l16 = lane & 15;
    int rgrp = lane >> 4;
    const float* Ls = L + ((long)b * N4 + ms * 16 + rgrp) * N4 + (long)w * 1024 + l16 * 4;
    int ks_loc_w = l16 >> 3, quad_w = (l16 >> 1) & 3, e0 = (l16 & 1) * 4;
    const unsigned short* Bbase = Tb0 + tb_idx(b, w * 32, 0, lane);
    unsigned short* LbBase = Lb + (((long)(b * 256 + ms) * 128 + w * 32) * 64 + lane) * 8;

    f32x4 acc0 = {0.f,0.f,0.f,0.f}, acc1 = {0.f,0.f,0.f,0.f};
    f32x4 v[4][4];
#pragma unroll
    for (int s = 0; s < 3; ++s)
#pragma unroll
        for (int j = 0; j < 4; ++j)
            v[s][j] = *(const f32x4*)(Ls + (long)j * 4 * N4 + s * 64);

#pragma unroll
    for (int it = 0; it < 16; ++it) {
        int sl = it & 3;
        if (it + 3 < 16) {
#pragma unroll
            for (int j = 0; j < 4; ++j)
                v[(it + 3) & 3][j] = *(const f32x4*)(Ls + (long)j * 4 * N4 + (it + 3) * 64);
        }
        short8 b00 = *(const short8*)(Bbase + (long)(it * 2 + 0) * 1024);
        short8 b01 = *(const short8*)(Bbase + (long)(it * 2 + 0) * 1024 + 512);
        short8 b10 = *(const short8*)(Bbase + (long)(it * 2 + 1) * 1024);
        short8 b11 = *(const short8*)(Bbase + (long)(it * 2 + 1) * 1024 + 512);
        unsigned short* Sb = &Sw[w][it & 1][0][0][0];
#pragma unroll
        for (int j = 0; j < 4; ++j) {
            u32x2 pk;
            pk[0] = (unsigned)f2b(v[sl][j][0]) | ((unsigned)f2b(v[sl][j][1]) << 16);
            pk[1] = (unsigned)f2b(v[sl][j][2]) | ((unsigned)f2b(v[sl][j][3]) << 16);
            int lane_o = quad_w * 16 + j * 4 + rgrp;
            *(u32x2*)(Sb + (ks_loc_w * 64 + lane_o) * 8 + e0) = pk;
        }
#pragma unroll
        for (int h = 0; h < 2; ++h) {
            short8 af = *(const short8*)(Sb + (h * 64 + lane) * 8);
            *(short8*)(LbBase + (long)(it * 2 + h) * 512) = af;  // 1KB wave-contiguous
            acc0 = __builtin_amdgcn_mfma_f32_16x16x32_bf16(af, h ? b10 : b00, acc0, 0, 0, 0);
            acc1 = __builtin_amdgcn_mfma_f32_16x16x32_bf16(af, h ? b11 : b01, acc1, 0, 0, 0);
        }
    }
    *(f32x4*)(P + ((((long)(w * 4 + b) * 256 + ms) * 2 + 0) * 64 + lane) * 4) = acc0;
    *(f32x4*)(P + ((((long)(w * 4 + b) * 256 + ms) * 2 + 1) * 64 + lane) * 4) = acc1;
}

// ---------------------------------------------------------------------------
// Passes 2..5: frag-layout streaming GEMM, 32 rows/wave (2 strips), 1:1 A:B
// load ratio, 4-slot prefetch.  grid 512 blocks (b, ms32) x 4 waves (s).
__global__ __launch_bounds__(256) void gemm_frag(const unsigned short* __restrict__ Lb,
                                                 const unsigned short* __restrict__ Tb,
                                                 float* __restrict__ P) {
    int tid = threadIdx.x, bid = blockIdx.x;
    int b = bid >> 7, ms32 = bid & 127;
    int s = tid >> 6, lane = tid & 63;
    const unsigned short* ApA = Lb + (((long)(b * 256 + ms32 * 2) * 128 + s * 32) * 64 + lane) * 8;
    const unsigned short* ApB = ApA + (long)128 * 64 * 8;   // next 16-row strip
    const unsigned short* Bp  = Tb + tb_idx(b, s * 32, 0, lane);

    f32x4 acc00 = {0.f,0.f,0.f,0.f}, acc01 = {0.f,0.f,0.f,0.f};
    f32x4 acc10 = {0.f,0.f,0.f,0.f}, acc11 = {0.f,0.f,0.f,0.f};
    short8 A0r[4], A1r[4], B0r[4], B1r[4];
#pragma unroll
    for (int i = 0; i < 4; ++i) {
        A0r[i] = *(const short8*)(ApA + (long)i * 512);
        A1r[i] = *(const short8*)(ApB + (long)i * 512);
        B0r[i] = *(const short8*)(Bp + (long)i * 1024);
        B1r[i] = *(const short8*)(Bp + (long)i * 1024 + 512);
    }
#pragma unroll 4
    for (int ks = 0; ks < 32; ++ks) {
        int sl = ks & 3;
        short8 a0 = A0r[sl], a1 = A1r[sl], b0 = B0r[sl], b1 = B1r[sl];
        if (ks + 4 < 32) {
            A0r[sl] = *(const short8*)(ApA + (long)(ks + 4) * 512);
            A1r[sl] = *(const short8*)(ApB + (long)(ks + 4) * 512);
            B0r[sl] = *(const short8*)(Bp + (long)(ks + 4) * 1024);
            B1r[sl] = *(const short8*)(Bp + (long)(ks + 4) * 1024 + 512);
        }
        acc00 = __builtin_amdgcn_mfma_f32_16x16x32_bf16(a0, b0, acc00, 0, 0, 0);
        acc01 = __builtin_amdgcn_mfma_f32_16x16x32_bf16(a0, b1, acc01, 0, 0, 0);
        acc10 = __builtin_amdgcn_mfma_f32_16x16x32_bf16(a1, b0, acc10, 0, 0, 0);
        acc11 = __builtin_amdgcn_mfma_f32_16x16x32_bf16(a1, b1, acc11, 0, 0, 0);
    }
    int ms_a = ms32 * 2, ms_b = ms32 * 2 + 1;
    *(f32x4*)(P + ((((long)(s * 4 + b) * 256 + ms_a) * 2 + 0) * 64 + lane) * 4) = acc00;
    *(f32x4*)(P + ((((long)(s * 4 + b) * 256 + ms_a) * 2 + 1) * 64 + lane) * 4) = acc01;
    *(f32x4*)(P + ((((long)(s * 4 + b) * 256 + ms_b) * 2 + 0) * 64 + lane) * 4) = acc10;
    *(f32x4*)(P + ((((long)(s * 4 + b) * 256 + ms_b) * 2 + 1) * 64 + lane) * 4) = acc11;
}

// ---------------------------------------------------------------------------
// T_k = a * (sum_s P[s]) + c * T_{k-2};  D-frag -> LDS -> Tb frag layout.
__global__ __launch_bounds__(256) void reduce_frag(const float* __restrict__ P,
                                                   const unsigned short* __restrict__ Tpp,
                                                   unsigned short* __restrict__ Tout,
                                                   float a, float c) {
    __shared__ float Sl[32][66];      // [f][n-local]
    int tid = threadIdx.x, bid = blockIdx.x;
    int b = bid >> 6, nc = bid & 63;
#pragma unroll
    for (int i = 0; i < 2; ++i) {
        int fid = i * 256 + tid;                  // (ms_l, h, lane)
        int ms_l = fid >> 7, h = (fid >> 6) & 1, lane = fid & 63;
        int quad = lane >> 4, l16 = lane & 15;
        long base = ((((long)b * 256 + nc * 4 + ms_l) * 2 + h) * 64 + lane) * 4;
        f32x4 sum = *(const f32x4*)(P + base);
#pragma unroll
        for (int s = 1; s < 4; ++s) {
            f32x4 v = *(const f32x4*)(P + base + (long)s * 524288);
#pragma unroll
            for (int e = 0; e < 4; ++e) sum[e] += v[e];
        }
        int f = h * 16 + l16, nl = ms_l * 16 + quad * 4;
#pragma unroll
        for (int r = 0; r < 4; ++r) Sl[f][nl + r] = sum[r];
    }
    __syncthreads();
    int ks_l = tid >> 7, half = (tid >> 6) & 1, lane = tid & 63;
    int quad = lane >> 4, l16 = lane & 15;
    int f = half * 16 + l16, nl = ks_l * 32 + quad * 8;
    long oidx = tb_idx(b, nc * 2 + ks_l, half, lane);
    const unsigned short* tp = Tpp ? (Tpp + oidx) : nullptr;
    i32x4 pk;
#pragma unroll
    for (int p = 0; p < 4; ++p) {
        float v0 = a * Sl[f][nl + p * 2];
        float v1 = a * Sl[f][nl + p * 2 + 1];
        if (tp) { v0 += c * b2f(tp[p * 2]); v1 += c * b2f(tp[p * 2 + 1]); }
        pk[p] = (unsigned)f2b(v0) | ((unsigned)f2b(v1) << 16);
    }
    *(i32x4*)(Tout + oidx) = pk;
}

// ---------------------------------------------------------------------------
// out[b][n][o] = sum_k sum_f T_k[b](f,n) * Wc[k][f][o]
__global__ __launch_bounds__(256) void proj(const unsigned short* __restrict__ T, // K slots, Tb layout
                                            const unsigned short* __restrict__ Wc,
                                            float* __restrict__ out) {
    __shared__ __align__(16) unsigned short Tl[192][72];
    __shared__ __align__(16) unsigned short Wl[192][64];
    int tid = threadIdx.x, bid = blockIdx.x;
    int b = bid >> 7; int rem = bid & 127;
    int nc = rem >> 1; long n0 = (long)nc * 64; int oh = rem & 1;
    const long T_SLOT = (long)BB * FF * N4;
#pragma unroll
    for (int it = 0; it < 6; ++it) {
        int row = it * 32 + (tid >> 3);    // kf index
        int col = (tid & 7) * 8;           // n-local
        int k = row >> 5, f = row & 31;
        int ks = nc * 2 + (col >> 5), half = f >> 4;
        int lane = ((col & 31) >> 3) * 16 + (f & 15);
        *(i32x4*)&Tl[row][col] = *(const i32x4*)(T + (long)k * T_SLOT + tb_idx(b, ks, half, lane));
        *(i32x4*)&Wl[row][col] = *(const i32x4*)(Wc + (long)row * OO + oh * 64 + col);
    }
    __syncthreads();
    int ol = tid & 63;
    int nb = (tid >> 6) * 16;
    float acc[16];
#pragma unroll
    for (int r = 0; r < 16; ++r) acc[r] = 0.f;
    for (int kf = 0; kf < 192; ++kf) {
        float w = b2f(Wl[kf][ol]);
#pragma unroll
        for (int rv = 0; rv < 2; ++rv) {
            short8 tv = *(const short8*)&Tl[kf][nb + rv * 8];
#pragma unroll
            for (int e = 0; e < 8; ++e)
                acc[rv * 8 + e] += b2f((unsigned short)tv[e]) * w;
        }
    }
    int o = oh * 64 + ol;
#pragma unroll
    for (int r = 0; r < 16; ++r)
        out[((long)b * N4 + n0 + nb + r) * OO + o] = acc[r];
}

// ---------------------------------------------------------------------------
extern "C" void kernel_launch(void* const* d_in, const int* in_sizes, int n_in,
                              void* d_out, int out_size, void* d_ws, size_t ws_size,
                              hipStream_t stream) {
    const float* x     = (const float*)d_in[0];
    const float* L     = (const float*)d_in[1];
    const float* W     = (const float*)d_in[2];
    const float* theta = (const float*)d_in[3];
    float* out = (float*)d_out;
    char* ws = (char*)d_ws;

    const size_t LB_BYTES = (size_t)BB * N4 * N4 * 2;     // 128 MiB
    const size_t T_SLOT   = (size_t)BB * FF * N4;         // elems per slot
    const size_t T_BYTES  = (size_t)KK * T_SLOT * 2;      // 6 MiB
    const size_t P_BYTES  = (size_t)4 * BB * N4 * FF * 4; // 8 MiB

    unsigned short* Lb = (unsigned short*)ws;
    unsigned short* T  = (unsigned short*)(ws + LB_BYTES);
    float*          P  = (float*)(ws + LB_BYTES + T_BYTES);
    unsigned short* Wc = (unsigned short*)(ws + LB_BYTES + T_BYTES + P_BYTES);

    make_wc<<<96, 256, 0, stream>>>(W, theta, Wc);
    x_to_t<<<256, 256, 0, stream>>>(x, T);          // slot 0 = frag-layout bf16(x^T)

    // pass 1: T1 = L @ T0, fused f32->frag transcode of L
    gemm_pass1<<<1024, 256, 0, stream>>>(L, Lb, T, P);
    reduce_frag<<<256, 256, 0, stream>>>(P, nullptr, T + 1 * T_SLOT, 1.f, 0.f);

    // passes 2..5: T_k = 2 L @ T_{k-1} - T_{k-2}
    for (int k = 2; k < KK; ++k) {
        gemm_frag<<<512, 256, 0, stream>>>(Lb, T + (k - 1) * T_SLOT, P);
        reduce_frag<<<256, 256, 0, stream>>>(P, T + (k - 2) * T_SLOT, T + k * T_SLOT, 2.f, -1.f);
    }

    proj<<<512, 256, 0, stream>>>(T, Wc, out);
}